// Round 2
// baseline (149.817 us; speedup 1.0000x reference)
//
#include <hip/hip_runtime.h>
#include <math.h>

#define HH 256
#define WW 256
#define BB 8
#define MM 256
#define NN (HH * WW)
#define PIX_PER_BLK 512
#define BLKS_PER_B (NN / PIX_PER_BLK)   // 128
#define NBLK (BB * BLKS_PER_B)          // 1024 blocks = 4 per CU

#define EPSI 1e-6f
#define MAXD 362.03867196751236f
#define EPS_OVER_MAXD (1e-6f / 362.03867196751236f)

static __device__ __forceinline__ float asqrt(float x) {
    return __builtin_amdgcn_sqrtf(x);   // single v_sqrt_f32 (~1 ulp)
}

// ws layout (uints): [0] counter | [16 .. 16+2047] gmin (INVERTED float bits,
// so memset-0 == +inf under atomicMax) | [2064 ..] per-block partial sums.
__global__ __launch_bounds__(256, 4) void whd_fused(
    const float* __restrict__ pm, const float* __restrict__ gt,
    const float* __restrict__ osz, float* __restrict__ out,
    unsigned* __restrict__ ws0)
{
    unsigned* ctr  = ws0;
    unsigned* gmin = ws0 + 16;                 // BB*MM entries
    unsigned* part = ws0 + 16 + BB * MM;       // NBLK*2 entries

    __shared__ float4   spx[PIX_PER_BLK];      // (y, x, s, p) per pixel, 8 KB
    __shared__ unsigned smin[MM];              // inverted bits (max == min)
    __shared__ float    swred[8];
    __shared__ float    tsum[BB];
    __shared__ float    gred[4];
    __shared__ int      lastFlag;

    const int tid = threadIdx.x;
    const int b   = blockIdx.y;
    const int blk = blockIdx.x;                // 0..127
    const int i   = tid >> 4;                  // pixel-group 0..15
    const int j   = tid & 15;                  // m-group 0..15

    const float nfY = osz[b * 2 + 0] * (1.0f / HH);
    const float nfX = osz[b * 2 + 1] * (1.0f / WW);

    // ---- stage this block's 512 pixels: (y, x, s=1/(p^4+eps'), p)
    {
        const int base = blk * PIX_PER_BLK;
        #pragma unroll
        for (int q = 0; q < 2; ++q) {
            const int l = tid * 2 + q;
            const int n = base + l;
            const float p  = pm[b * NN + n];
            const float p2 = p * p;
            const float s  = 1.0f / (p2 * p2 + EPS_OVER_MAXD);
            spx[l] = make_float4((float)(n >> 8) * nfY, (float)(n & 255) * nfX, s, p);
        }
        smin[tid] = 0u;   // == +inf in inverted representation
    }

    // ---- this thread's 16 GT points -> registers (loop-invariant)
    float gy[16], gx[16];
    {
        const float4* g4 = (const float4*)(gt + (b * MM + j * 16) * 2);
        #pragma unroll
        for (int q = 0; q < 8; ++q) {
            const float4 v = g4[q];
            gy[q * 2]     = v.x * nfY;  gx[q * 2]     = v.y * nfX;
            gy[q * 2 + 1] = v.z * nfY;  gx[q * 2 + 1] = v.w * nfX;
        }
    }

    float cm[16];
    #pragma unroll
    for (int k = 0; k < 16; ++k) cm[k] = INFINITY;

    float sum0 = 0.0f, sum1 = 0.0f;

    __syncthreads();

    // ---- main loop: 32 pixel-iters x 16 m = 512 pairs/thread, 8 VALU/pair
    for (int iter = 0; iter < PIX_PER_BLK / 16; ++iter) {
        const float4 px = spx[(iter << 4) | i];   // broadcast within j-group
        const float y = px.x, x = px.y, s = px.z, p = px.w;
        const float c = EPSI * s;
        float rmin = INFINITY;
        #pragma unroll
        for (int k = 0; k < 16; ++k) {
            const float dy = y - gy[k];
            const float dx = x - gx[k];
            const float d2 = fmaf(dy, dy, dx * dx);
            rmin = fminf(rmin, d2);
            const float v = fmaf(asqrt(d2), s, c);    // (d+EPS)*s
            cm[k] = fminf(cm[k], v);
        }
        // min over the 16 j-lanes (covers all 256 m) — lanes are contiguous
        rmin = fminf(rmin, __shfl_xor(rmin, 1, 16));
        rmin = fminf(rmin, __shfl_xor(rmin, 2, 16));
        rmin = fminf(rmin, __shfl_xor(rmin, 4, 16));
        rmin = fminf(rmin, __shfl_xor(rmin, 8, 16));
        sum0 += p;                       // duplicated x16 across j; /16 later
        sum1 = fmaf(p, asqrt(rmin), sum1);
    }

    // ---- column (per-m) minima: reduce across i within wave, then LDS, then global
    #pragma unroll
    for (int k = 0; k < 16; ++k) {
        float m = cm[k];
        m = fminf(m, __shfl_xor(m, 16, 64));
        m = fminf(m, __shfl_xor(m, 32, 64));
        cm[k] = m;
    }
    if ((tid & 63) < 16) {               // one lane per (wave, j)
        #pragma unroll
        for (int k = 0; k < 16; ++k)
            atomicMax(&smin[(j << 4) + k], ~__float_as_uint(cm[k]));
    }

    // ---- term1 partial sums: wave reduce then block
    #pragma unroll
    for (int off = 32; off; off >>= 1) {
        sum0 += __shfl_down(sum0, off, 64);
        sum1 += __shfl_down(sum1, off, 64);
    }
    if ((tid & 63) == 0) { swred[(tid >> 6) * 2] = sum0; swred[(tid >> 6) * 2 + 1] = sum1; }
    __syncthreads();                     // also orders the smin atomics

    const int blin = b * BLKS_PER_B + blk;
    if (tid == 0) {
        const float s0 = (swred[0] + swred[2] + swred[4] + swred[6]) * (1.0f / 16.0f);
        const float s1 = (swred[1] + swred[3] + swred[5] + swred[7]) * (1.0f / 16.0f);
        atomicExch(&part[blin * 2 + 0], __float_as_uint(s0));
        atomicExch(&part[blin * 2 + 1], __float_as_uint(s1));
    }
    atomicMax(&gmin[b * MM + tid], smin[tid]);   // device-scope

    // ---- last-block final combine
    __threadfence();
    if (tid == 0) {
        const unsigned old = atomicAdd(ctr, 1u);
        lastFlag = (old == NBLK - 1);
    }
    __syncthreads();
    if (!lastFlag) return;
    __threadfence();

    // term2: mean of clipped per-(b,m) minima (2048 entries, atomic reads)
    float gacc = 0.0f;
    #pragma unroll
    for (int q = 0; q < 8; ++q) {
        const unsigned bits = ~atomicOr(&gmin[q * 256 + tid], 0u);
        const float v = __uint_as_float(bits);
        gacc += fminf(fmaxf(v, 0.0f), MAXD);
    }
    #pragma unroll
    for (int off = 32; off; off >>= 1) gacc += __shfl_down(gacc, off, 64);
    if ((tid & 63) == 0) gred[tid >> 6] = gacc;

    // term1: per-batch ratios from per-block partials
    {
        const int bb = tid >> 5, r = tid & 31;
        float s0 = 0.0f, s1 = 0.0f;
        #pragma unroll
        for (int q = 0; q < 4; ++q) {
            const int bl = bb * BLKS_PER_B + r + q * 32;
            s0 += __uint_as_float(atomicOr(&part[bl * 2 + 0], 0u));
            s1 += __uint_as_float(atomicOr(&part[bl * 2 + 1], 0u));
        }
        #pragma unroll
        for (int off = 16; off; off >>= 1) {
            s0 += __shfl_down(s0, off, 32);
            s1 += __shfl_down(s1, off, 32);
        }
        if (r == 0) tsum[bb] = s1 / (s0 + EPSI);
    }
    __syncthreads();
    if (tid == 0) {
        float t1 = 0.0f;
        #pragma unroll
        for (int q = 0; q < BB; ++q) t1 += tsum[q];
        const float g = gred[0] + gred[1] + gred[2] + gred[3];
        out[0] = t1 * (1.0f / BB) + g * (1.0f / (BB * MM));
    }
}

extern "C" void kernel_launch(void* const* d_in, const int* in_sizes, int n_in,
                              void* d_out, int out_size, void* d_ws, size_t ws_size,
                              hipStream_t stream) {
    const float* pm  = (const float*)d_in[0];   // [B, H, W]
    const float* gt  = (const float*)d_in[1];   // [B, M, 2]
    const float* osz = (const float*)d_in[2];   // [B, 2]
    float* out = (float*)d_out;
    unsigned* ws0 = (unsigned*)d_ws;

    // counter + gmin zero-init (gmin stores inverted bits: 0 == +inf)
    hipMemsetAsync(ws0, 0, (16 + BB * MM) * sizeof(unsigned), stream);

    dim3 grid(BLKS_PER_B, BB);
    whd_fused<<<grid, 256, 0, stream>>>(pm, gt, osz, out, ws0);
}

// Round 3
// 120.029 us; speedup vs baseline: 1.2482x; 1.2482x over previous
//
#include <hip/hip_runtime.h>
#include <math.h>

#define HH 256
#define WW 256
#define BB 8
#define MM 256
#define NN (HH * WW)
#define PP 4                              // pixels per thread (same row)
#define TPB 256
#define PIX_PER_BLK (TPB * PP)            // 1024 = 4 rows
#define BLKS_PER_B (NN / PIX_PER_BLK)     // 64
#define NBLK (BB * BLKS_PER_B)            // 512 blocks = 2 per CU

#define EPSI 1e-6f
#define MAXD 362.03867196751236f
#define EPS_OVER_MAXD (1e-6f / 362.03867196751236f)

static __device__ __forceinline__ float asqrt(float x) {
    return __builtin_amdgcn_sqrtf(x);     // single v_sqrt_f32
}

// ws layout (uints): [0] counter | [16..16+2047] gmin (INVERTED float bits:
// memset-0 == +inf under unsigned atomicMax) | [2064..] per-block partials.
__global__ __launch_bounds__(256, 2) void whd_fused(
    const float* __restrict__ pm, const float* __restrict__ gt,
    const float* __restrict__ osz, float* __restrict__ out,
    unsigned* __restrict__ ws0)
{
    unsigned* ctr  = ws0;
    unsigned* gmin = ws0 + 16;                 // BB*MM
    unsigned* part = ws0 + 16 + BB * MM;       // NBLK*2

    __shared__ float2 sgt[MM];    // scaled GT points (2 KB)
    __shared__ int    smin[MM];   // per-m block min, float bits (>=0 -> int order ok)
    __shared__ float  swred[8];
    __shared__ float  tsum[BB];
    __shared__ float  gred[4];
    __shared__ int    lastFlag;

    const int tid = threadIdx.x;
    const int blk = blockIdx.x;   // 0..63
    const int b   = blockIdx.y;

    const float nfY = osz[b * 2 + 0] * (1.0f / HH);
    const float nfX = osz[b * 2 + 1] * (1.0f / WW);

    // stage scaled GT + init column minima
    {
        const float2 g = ((const float2*)gt)[b * MM + tid];
        sgt[tid]  = make_float2(g.x * nfY, g.y * nfX);
        smin[tid] = 0x7F800000;   // +inf
    }

    // this thread's 4 pixels: one row, 4 consecutive cols (coalesced float4)
    const int   row  = blk * 4 + (tid >> 6);
    const int   col0 = (tid & 63) * 4;
    const float y    = (float)row * nfY;

    const float4 pv = *(const float4*)(pm + b * NN + row * WW + col0);
    float p[PP] = {pv.x, pv.y, pv.z, pv.w};
    float xs[PP], sc[PP], c4[PP], mind2[PP];
    #pragma unroll
    for (int c = 0; c < PP; ++c) {
        xs[c] = (float)(col0 + c) * nfX;
        const float p2 = p[c] * p[c];
        sc[c]    = 1.0f / (p2 * p2 + EPS_OVER_MAXD);   // 1/(p^4 + EPS/MAXD)
        c4[c]    = EPSI * sc[c];
        mind2[c] = INFINITY;
    }

    __syncthreads();

    // ---- main loop: 256 m-iters x 4 pixels; zero cross-lane ops.
    // Rotation (mm+tid)&255: per-lane distinct m -> conflict-free ds_read_b64
    // and distinct-address LDS atomics.
    #pragma unroll 2
    for (int mm = 0; mm < MM; ++mm) {
        const int    m = (mm + tid) & (MM - 1);
        const float2 g = sgt[m];
        float ey = y - g.x;  ey *= ey;
        float cmin = INFINITY;
        #pragma unroll
        for (int c = 0; c < PP; ++c) {
            const float dx = xs[c] - g.y;
            const float d2 = fmaf(dx, dx, ey);
            mind2[c] = fminf(mind2[c], d2);
            const float v = fmaf(asqrt(d2), sc[c], c4[c]);   // (d+EPS)/(p^4+..)
            cmin = fminf(cmin, v);
        }
        atomicMin(&smin[m], __float_as_int(cmin));
    }

    // ---- term1 partials (thread-exclusive pixels -> plain wave reduce once)
    float sum0 = (p[0] + p[1]) + (p[2] + p[3]);
    float sum1 = 0.0f;
    #pragma unroll
    for (int c = 0; c < PP; ++c) sum1 = fmaf(p[c], asqrt(mind2[c]), sum1);

    #pragma unroll
    for (int off = 32; off; off >>= 1) {
        sum0 += __shfl_down(sum0, off, 64);
        sum1 += __shfl_down(sum1, off, 64);
    }
    if ((tid & 63) == 0) { swred[(tid >> 6) * 2] = sum0; swred[(tid >> 6) * 2 + 1] = sum1; }
    __syncthreads();   // also orders all smin atomics

    const int blin = b * BLKS_PER_B + blk;
    if (tid == 0) {
        const float s0 = (swred[0] + swred[2]) + (swred[4] + swred[6]);
        const float s1 = (swred[1] + swred[3]) + (swred[5] + swred[7]);
        atomicExch(&part[blin * 2 + 0], __float_as_uint(s0));
        atomicExch(&part[blin * 2 + 1], __float_as_uint(s1));
    }
    // merge block's per-m minima into global (inverted bits, unsigned max)
    atomicMax(&gmin[b * MM + tid], ~(unsigned)smin[tid]);

    // ---- last-block combine
    __threadfence();
    if (tid == 0) lastFlag = (atomicAdd(ctr, 1u) == NBLK - 1);
    __syncthreads();
    if (!lastFlag) return;
    __threadfence();

    // term2: mean of clipped per-(b,m) minima
    float gacc = 0.0f;
    #pragma unroll
    for (int q = 0; q < BB; ++q) {
        const float v = __uint_as_float(~atomicOr(&gmin[q * MM + tid], 0u));
        gacc += fminf(fmaxf(v, 0.0f), MAXD);
    }
    #pragma unroll
    for (int off = 32; off; off >>= 1) gacc += __shfl_down(gacc, off, 64);
    if ((tid & 63) == 0) gred[tid >> 6] = gacc;

    // term1: per-batch ratios from per-block partials (8 batches x 32 lanes)
    {
        const int bb = tid >> 5, r = tid & 31;
        float s0 = 0.0f, s1 = 0.0f;
        #pragma unroll
        for (int q = 0; q < BLKS_PER_B / 32; ++q) {   // 2
            const int bl = bb * BLKS_PER_B + r + q * 32;
            s0 += __uint_as_float(atomicOr(&part[bl * 2 + 0], 0u));
            s1 += __uint_as_float(atomicOr(&part[bl * 2 + 1], 0u));
        }
        #pragma unroll
        for (int off = 16; off; off >>= 1) {
            s0 += __shfl_down(s0, off, 32);
            s1 += __shfl_down(s1, off, 32);
        }
        if (r == 0) tsum[bb] = s1 / (s0 + EPSI);
    }
    __syncthreads();
    if (tid == 0) {
        float t1 = 0.0f;
        #pragma unroll
        for (int q = 0; q < BB; ++q) t1 += tsum[q];
        const float g = (gred[0] + gred[1]) + (gred[2] + gred[3]);
        out[0] = t1 * (1.0f / BB) + g * (1.0f / (BB * MM));
    }
}

extern "C" void kernel_launch(void* const* d_in, const int* in_sizes, int n_in,
                              void* d_out, int out_size, void* d_ws, size_t ws_size,
                              hipStream_t stream) {
    const float* pm  = (const float*)d_in[0];   // [B, H, W]
    const float* gt  = (const float*)d_in[1];   // [B, M, 2]
    const float* osz = (const float*)d_in[2];   // [B, 2]
    float* out = (float*)d_out;
    unsigned* ws0 = (unsigned*)d_ws;

    // counter + gmin zero-init (gmin inverted bits: 0 == +inf)
    hipMemsetAsync(ws0, 0, (16 + BB * MM) * sizeof(unsigned), stream);

    dim3 grid(BLKS_PER_B, BB);
    whd_fused<<<grid, 256, 0, stream>>>(pm, gt, osz, out, ws0);
}